// Round 9
// baseline (539.881 us; speedup 1.0000x reference)
//
#include <hip/hip_runtime.h>
#include <math.h>

#define BB 8
#define CC 128
#define HH 64
#define WW 64
#define NPTS 9
#define OUTC 256
#define HW (HH*WW)
#define KTOT (CC*NPTS)   // 1152
#define BK 288           // 32 channels * 9 taps per K-chunk
#define AP 290           // Atile row in bf16 elems: 580 B = 145 words (ODD -> 2-way=free)
#define WROWS 6          // x row window: global rows h-2 .. h+3
#define NCH 16           // channels staged per phase = 8 pairs

typedef __attribute__((ext_vector_type(8))) short bf16x8;
typedef __attribute__((ext_vector_type(4))) float f32x4;

// bf16 weights, k-order permuted: k = cb*288 + pair*18 + n*2 + half,
// where channel c = cb*32 + pair*2 + half, tap n = ky*3+kx.
__device__ unsigned short g_wT[OUTC * KTOT];   // main conv weights
__device__ unsigned short g_woT[32 * KTOT];    // offset(18)+mask(9)+zero(5)

__device__ __forceinline__ unsigned short f2bf(float f) {
    unsigned int u = __builtin_bit_cast(unsigned int, f);
    unsigned int r = (u + 0x7FFFu + ((u >> 16) & 1u)) >> 16;   // RNE
    return (unsigned short)r;
}

__device__ __forceinline__ unsigned cvtpk(float lo, float hi) {   // {bf16(lo), bf16(hi)<<16}
    unsigned r;
    asm("v_cvt_pk_bf16_f32 %0, %1, %2" : "=v"(r) : "v"(lo), "v"(hi));
    return r;
}
__device__ __forceinline__ float bflo(unsigned w) { return __builtin_bit_cast(float, w << 16); }
__device__ __forceinline__ float bfhi(unsigned w) { return __builtin_bit_cast(float, w & 0xFFFF0000u); }

__device__ __forceinline__ int orig_k(int k) {      // permuted k -> original c*9+n
    int cb = k / BK, r = k % BK;
    int pair = r / 18, r2 = r % 18;
    int n = r2 >> 1, half = r2 & 1;
    return (cb * 32 + pair * 2 + half) * NPTS + n;
}

__global__ __launch_bounds__(256) void prep_kernel(
    const float* __restrict__ wo, const float* __restrict__ wm,
    const float* __restrict__ wc)
{
    int idx = blockIdx.x * 256 + threadIdx.x;
    const int T1 = 32 * KTOT;
    if (idx < T1) {
        int nn = idx / KTOT, k = idx - nn * KTOT;
        int ok = orig_k(k);
        float v = (nn < 18) ? wo[nn * KTOT + ok]
                            : (nn < 27 ? wm[(nn - 18) * KTOT + ok] : 0.f);
        g_woT[idx] = f2bf(v);
    } else if (idx < T1 + OUTC * KTOT) {
        int j = idx - T1;
        int oc = j / KTOT, k = j - oc * KTOT;
        g_wT[j] = f2bf(wc[oc * KTOT + orig_k(k)]);
    }
}

// T14 async-stage: 12 scalar coalesced loads per thread (2 channels x 6 rows).
struct PF { float a[WROWS], b[WROWS]; };

__device__ __forceinline__ void issue(PF& pf, const float* __restrict__ xb,
                                      int h, int g, int tid) {
    if (g > 15) return;                       // phases 0..15 (8 per pass)
    int cb = (g >> 1) & 3, s = g & 1;
    int pair = tid >> 6, sub = tid & 63;      // pair==wave id -> coalesced
    const float* pA = xb + (size_t)(cb * 32 + s * NCH + pair * 2) * HW + sub;
    #pragma unroll
    for (int k = 0; k < WROWS; ++k) {
        int gr = h - 2 + k;
        bool v = (gr >= 0) & (gr < HH);
        pf.a[k] = v ? pA[gr * WW] : 0.f;
        pf.b[k] = v ? pA[HW + gr * WW] : 0.f;
    }
}

__device__ __forceinline__ void commit(unsigned* buf, const PF& pf, int tid) {
    unsigned* wp = buf + (tid >> 6) * 384 + (tid & 63);   // stride-1 across lanes
    #pragma unroll
    for (int k = 0; k < WROWS; ++k) wp[k * 64] = cvtpk(pf.a[k], pf.b[k]);
}

// 512 threads = 8 waves; LDS 61.7 KB -> 2 blocks/CU, 16 waves/CU.
__global__ __launch_bounds__(512) __attribute__((amdgpu_waves_per_eu(4, 4)))
void fused_kernel(
    const float* __restrict__ x,
    const float* __restrict__ b_offset, const float* __restrict__ b_mask,
    const float* __restrict__ bn_gamma, const float* __restrict__ bn_beta,
    const float* __restrict__ bn_mean,  const float* __restrict__ bn_var,
    float* __restrict__ out)
{
    __shared__ unsigned short Atile[64][AP];     // 37120 B
    __shared__ unsigned win2[2][8 * 384];        // 2 x 12288 B: paired-bf16 window
    float* ovf = (float*)&win2[0][0];            // px/py/m overlay between passes

    int blk = blockIdx.x;
    int b = blk >> 6, h = blk & 63;
    int tid  = threadIdx.x;
    int lane = tid & 63;
    int wv   = __builtin_amdgcn_readfirstlane(tid >> 6);  // wave 0..7
    int l15  = lane & 15;
    int kg   = lane >> 4;
    int spix = lane;

    const float* xb = x + (size_t)b * CC * HW;
    unsigned* AtU = (unsigned*)&Atile[0][0];     // row stride 145 uints (odd -> spread)

    // ================= PASS A: offset/mask conv (M=64,N=32,K=1152) =========
    int mi_a = wv & 3, nf_a = wv >> 2;
    f32x4 s1acc = {0.f, 0.f, 0.f, 0.f};

    int g = 0;
    PF pf; issue(pf, xb, h, 0, tid);
    for (int cb = 0; cb < 4; ++cb) {
        for (int s = 0; s < 2; ++s) {
            commit(win2[g & 1], pf, tid);
            __syncthreads();                 // window ready; prev-phase readers done
            issue(pf, xb, h, g + 1, tid);
            // build patch: word already holds the channel pair
            int cpair = s * 8 + wv;
            const unsigned* base = &win2[g & 1][wv * 384];
            #pragma unroll
            for (int tap = 0; tap < 9; ++tap) {
                int ky = tap / 3, kx = tap % 3;
                int col  = spix + kx - 1;
                int colc = min(max(col, 0), WW - 1);
                unsigned w = base[(ky + 1) * 64 + colc];
                w = (col >= 0 && col < WW) ? w : 0u;
                AtU[spix * 145 + cpair * 9 + tap] = w;
            }
            ++g;
        }
        __syncthreads();                     // Atile complete
        for (int q = 0; q < 9; ++q) {
            int koff = q * 32 + kg * 8;
            bf16x8 af = *(const bf16x8*)&Atile[mi_a * 16 + l15][koff];
            int nn = nf_a * 16 + l15;
            bf16x8 bfr = *(const bf16x8*)&g_woT[nn * KTOT + cb * BK + koff];
            s1acc = __builtin_amdgcn_mfma_f32_16x16x32_bf16(af, bfr, s1acc, 0, 0, 0);
        }
    }

    // ---- pass-A epilogue into overlay (win2[0] dead) -----------------------
    #pragma unroll
    for (int j = 0; j < 4; ++j) {
        float val = s1acc[j];
        int nn   = nf_a * 16 + l15;
        int pixl = mi_a * 16 + kg * 4 + j;
        if (nn < 9) {
            ovf[nn * 64 + pixl] = val + b_offset[nn] + (float)(nn / 3 - 1) + (float)(h + 1);
        } else if (nn < 18) {
            int n = nn - 9;
            ovf[576 + n * 64 + pixl] = val + b_offset[nn] + (float)(n % 3 - 1) + (float)(pixl + 1);
        } else if (nn < 27) {
            int n = nn - 18;
            float sg = val + b_mask[n];
            ovf[1152 + n * 64 + pixl] = 1.f / (1.f + expf(-sg));
        }
    }
    __syncthreads();

    // ================= bilinear params -> REGISTERS (all 512 threads) =======
    float gw0[9], gw1[9], gw2[9], gw3[9];
    unsigned pk[9];
    #pragma unroll
    for (int n = 0; n < NPTS; ++n) {
        float px = ovf[n * 64 + spix];
        float py = ovf[576 + n * 64 + spix];
        float m  = ovf[1152 + n * 64 + spix];
        float fx = floorf(px), fy = floorf(py);
        float qltx = fminf(fmaxf(fx,       0.f), 65.f);
        float qlty = fminf(fmaxf(fy,       0.f), 65.f);
        float qrbx = fminf(fmaxf(fx + 1.f, 0.f), 65.f);
        float qrby = fminf(fmaxf(fy + 1.f, 0.f), 65.f);
        float pxc  = fminf(fmaxf(px, 0.f), 65.f);
        float pyc  = fminf(fmaxf(py, 0.f), 65.f);
        float glt = (1.f + (qltx - pxc)) * (1.f + (qlty - pyc)) * m;
        float grb = (1.f - (qrbx - pxc)) * (1.f - (qrby - pyc)) * m;
        float glb = (1.f + (qltx - pxc)) * (1.f - (qrby - pyc)) * m;
        float grt = (1.f - (qrbx - pxc)) * (1.f + (qlty - pyc)) * m;
        int i0 = (int)qltx - 1, j0 = (int)qlty - 1;
        int i1 = (int)qrbx - 1, j1 = (int)qrby - 1;
        bool v00 = (i0 >= 0) & (i0 < HH) & (j0 >= 0) & (j0 < WW);
        bool v11 = (i1 >= 0) & (i1 < HH) & (j1 >= 0) & (j1 < WW);
        bool v01 = (i0 >= 0) & (i0 < HH) & (j1 >= 0) & (j1 < WW);
        bool v10 = (i1 >= 0) & (i1 < HH) & (j0 >= 0) & (j0 < WW);
        gw0[n] = v00 ? glt : 0.f;   // (i0,j0)
        gw1[n] = v11 ? grb : 0.f;   // (i1,j1)
        gw2[n] = v01 ? glb : 0.f;   // (i0,j1)
        gw3[n] = v10 ? grt : 0.f;   // (i1,j0)
        bool okr0 = ((i0 >= h - 2) & (i0 <= h + 3)) | !(v00 | v01);
        bool okr1 = ((i1 >= h - 2) & (i1 <= h + 3)) | !(v11 | v10);
        bool ok = okr0 & okr1;
        int r0w = min(max(i0 - (h - 2), 0), WROWS - 1);
        int r1w = min(max(i1 - (h - 2), 0), WROWS - 1);
        int r0g = min(max(i0, 0), HH - 1);
        int r1g = min(max(i1, 0), HH - 1);
        int j0c = min(max(j0, 0), WW - 1);
        int j1c = min(max(j1, 0), WW - 1);
        int o  = ok ? (r0w * WW + j0c) : (r0g * WW + j0c);
        int dr = ok ? (r1w - r0w) : (r1g - r0g);
        int dj = j1c - j0c;
        pk[n] = (unsigned)o | ((unsigned)(dr + 64) << 13)
              | ((unsigned)(dj + 64) << 20) | ((unsigned)ok << 27);
    }
    __syncthreads();                         // overlay dead; pass B may commit

    // ================= PASS B: main GEMM (M=64, N=256, K=1152) ==============
    f32x4 acc[4][2];
    #pragma unroll
    for (int mi = 0; mi < 4; ++mi)
        #pragma unroll
        for (int ni = 0; ni < 2; ++ni)
            acc[mi][ni] = (f32x4){0.f, 0.f, 0.f, 0.f};

    int oc0 = wv * 32;

    for (int cb = 0; cb < 4; ++cb) {
        for (int s = 0; s < 2; ++s) {
            commit(win2[g & 1], pf, tid);
            __syncthreads();
            issue(pf, xb, h, g + 1, tid);
            int cpair = s * 8 + wv;
            const unsigned* base = &win2[g & 1][wv * 384];
            const float* xgA = xb + (size_t)(cb * 32 + s * NCH + wv * 2) * HW;
            const float* xgB = xgA + HW;
            #pragma unroll
            for (int n = 0; n < NPTS; ++n) {
                unsigned p = pk[n];
                int o  = p & 0x1FFF;
                int d1 = ((int)((p >> 13) & 0x7F) - 64) * WW;
                int d2 = (int)((p >> 20) & 0x7F) - 64;
                float v0, v1;
                if (p & (1u << 27)) {        // in-window: paired bf16 reads
                    unsigned w00 = base[o];
                    unsigned w11 = base[o + d1 + d2];
                    unsigned w01 = base[o + d2];
                    unsigned w10 = base[o + d1];
                    v0 =       gw0[n] * bflo(w00);
                    v0 = fmaf(gw1[n], bflo(w11), v0);
                    v0 = fmaf(gw2[n], bflo(w01), v0);
                    v0 = fmaf(gw3[n], bflo(w10), v0);
                    v1 =       gw0[n] * bfhi(w00);
                    v1 = fmaf(gw1[n], bfhi(w11), v1);
                    v1 = fmaf(gw2[n], bfhi(w01), v1);
                    v1 = fmaf(gw3[n], bfhi(w10), v1);
                } else {                     // rare: f32 global corners
                    v0 =       gw0[n] * xgA[o];
                    v0 = fmaf(gw1[n], xgA[o + d1 + d2], v0);
                    v0 = fmaf(gw2[n], xgA[o + d2], v0);
                    v0 = fmaf(gw3[n], xgA[o + d1], v0);
                    v1 =       gw0[n] * xgB[o];
                    v1 = fmaf(gw1[n], xgB[o + d1 + d2], v1);
                    v1 = fmaf(gw2[n], xgB[o + d2], v1);
                    v1 = fmaf(gw3[n], xgB[o + d1], v1);
                }
                AtU[spix * 145 + cpair * 9 + n] = cvtpk(v0, v1);
            }
            ++g;
        }
        __syncthreads();                     // Atile complete
        for (int q = 0; q < 9; ++q) {
            int koff = q * 32 + kg * 8;
            bf16x8 af[4];
            #pragma unroll
            for (int mi = 0; mi < 4; ++mi)
                af[mi] = *(const bf16x8*)&Atile[mi * 16 + l15][koff];
            #pragma unroll
            for (int ni = 0; ni < 2; ++ni) {
                int oc = oc0 + ni * 16 + l15;
                bf16x8 bfr = *(const bf16x8*)&g_wT[oc * KTOT + cb * BK + koff];
                #pragma unroll
                for (int mi = 0; mi < 4; ++mi)
                    acc[mi][ni] = __builtin_amdgcn_mfma_f32_16x16x32_bf16(af[mi], bfr, acc[mi][ni], 0, 0, 0);
            }
        }
    }

    // ================= epilogue: BN + ReLU, float4 stores ===================
    #pragma unroll
    for (int ni = 0; ni < 2; ++ni) {
        int oc = oc0 + ni * 16 + l15;
        float inv   = 1.f / sqrtf(bn_var[oc] + 1e-5f);
        float scale = bn_gamma[oc] * inv;
        float shift = bn_beta[oc] - bn_mean[oc] * scale;
        float* op = out + ((size_t)b * OUTC + oc) * HW + h * WW + kg * 4;
        #pragma unroll
        for (int mi = 0; mi < 4; ++mi) {
            f32x4 o4;
            #pragma unroll
            for (int j = 0; j < 4; ++j) {
                float v = fmaf(acc[mi][ni][j], scale, shift);
                o4[j] = v > 0.f ? v : 0.f;
            }
            *(f32x4*)(op + mi * 16) = o4;
        }
    }
}

extern "C" void kernel_launch(void* const* d_in, const int* in_sizes, int n_in,
                              void* d_out, int out_size, void* d_ws, size_t ws_size,
                              hipStream_t stream) {
    (void)in_sizes; (void)n_in; (void)out_size; (void)d_ws; (void)ws_size;
    const float* x        = (const float*)d_in[0];
    const float* w_offset = (const float*)d_in[1];
    const float* b_offset = (const float*)d_in[2];
    const float* w_mask   = (const float*)d_in[3];
    const float* b_mask   = (const float*)d_in[4];
    const float* w_conv   = (const float*)d_in[5];
    const float* bn_gamma = (const float*)d_in[6];
    const float* bn_beta  = (const float*)d_in[7];
    const float* bn_mean  = (const float*)d_in[8];
    const float* bn_var   = (const float*)d_in[9];
    float* out = (float*)d_out;

    int prep_elems = 32 * KTOT + OUTC * KTOT;
    prep_kernel<<<(prep_elems + 255) / 256, 256, 0, stream>>>(w_offset, w_mask, w_conv);
    fused_kernel<<<BB * HH, 512, 0, stream>>>(x, b_offset, b_mask,
                                              bn_gamma, bn_beta, bn_mean, bn_var, out);
}

// Round 10
// 93.135 us; speedup vs baseline: 5.7968x; 5.7968x over previous
//
#include <hip/hip_runtime.h>
#include <math.h>

#define BB 8
#define CC 128
#define HH 64
#define WW 64
#define NPTS 9
#define OUTC 256
#define HW (HH*WW)
#define KTOT (CC*NPTS)   // 1152
#define BK 288           // 32 channels * 9 taps per K-chunk
#define AP 290           // Atile row in bf16 elems: 580 B = 145 words (ODD -> 2-way=free)
#define WROWS 6          // x row window: global rows h-2 .. h+3
#define NCH 16           // channels staged per phase = 8 pairs

typedef __attribute__((ext_vector_type(8))) short bf16x8;
typedef __attribute__((ext_vector_type(4))) float f32x4;

// bf16 weights, k-order permuted: k = cb*288 + pair*18 + n*2 + half,
// where channel c = cb*32 + pair*2 + half, tap n = ky*3+kx.
__device__ unsigned short g_wT[OUTC * KTOT];   // main conv weights
__device__ unsigned short g_woT[32 * KTOT];    // offset(18)+mask(9)+zero(5)

__device__ __forceinline__ unsigned short f2bf(float f) {
    unsigned int u = __builtin_bit_cast(unsigned int, f);
    unsigned int r = (u + 0x7FFFu + ((u >> 16) & 1u)) >> 16;   // RNE
    return (unsigned short)r;
}

__device__ __forceinline__ unsigned cvtpk(float lo, float hi) {   // {bf16(lo), bf16(hi)<<16}
    unsigned r;
    asm("v_cvt_pk_bf16_f32 %0, %1, %2" : "=v"(r) : "v"(lo), "v"(hi));
    return r;
}
__device__ __forceinline__ float bflo(unsigned w) { return __builtin_bit_cast(float, w << 16); }
__device__ __forceinline__ float bfhi(unsigned w) { return __builtin_bit_cast(float, w & 0xFFFF0000u); }

__device__ __forceinline__ int orig_k(int k) {      // permuted k -> original c*9+n
    int cb = k / BK, r = k % BK;
    int pair = r / 18, r2 = r % 18;
    int n = r2 >> 1, half = r2 & 1;
    return (cb * 32 + pair * 2 + half) * NPTS + n;
}

__global__ __launch_bounds__(256) void prep_kernel(
    const float* __restrict__ wo, const float* __restrict__ wm,
    const float* __restrict__ wc)
{
    int idx = blockIdx.x * 256 + threadIdx.x;
    const int T1 = 32 * KTOT;
    if (idx < T1) {
        int nn = idx / KTOT, k = idx - nn * KTOT;
        int ok = orig_k(k);
        float v = (nn < 18) ? wo[nn * KTOT + ok]
                            : (nn < 27 ? wm[(nn - 18) * KTOT + ok] : 0.f);
        g_woT[idx] = f2bf(v);
    } else if (idx < T1 + OUTC * KTOT) {
        int j = idx - T1;
        int oc = j / KTOT, k = j - oc * KTOT;
        g_wT[j] = f2bf(wc[oc * KTOT + orig_k(k)]);
    }
}

// T14 async-stage: 12 scalar coalesced loads per thread (2 channels x 6 rows).
// PF = 12 VGPRs; R9 lesson: 512-thread blocks get squeezed to the 64-VGPR
// tier regardless of waves_per_eu, so TOTAL persistent state must stay < 64.
struct PF { float a[WROWS], b[WROWS]; };

__device__ __forceinline__ void issue(PF& pf, const float* __restrict__ xb,
                                      int h, int g, int tid) {
    if (g > 15) return;                       // phases 0..15 (8 per pass)
    int cb = (g >> 1) & 3, s = g & 1;
    int pair = tid >> 6, sub = tid & 63;      // pair==wave id -> coalesced
    const float* pA = xb + (size_t)(cb * 32 + s * NCH + pair * 2) * HW + sub;
    #pragma unroll
    for (int k = 0; k < WROWS; ++k) {
        int gr = h - 2 + k;
        bool v = (gr >= 0) & (gr < HH);
        pf.a[k] = v ? pA[gr * WW] : 0.f;
        pf.b[k] = v ? pA[HW + gr * WW] : 0.f;
    }
}

__device__ __forceinline__ void commit(unsigned* buf, const PF& pf, int tid) {
    unsigned* wp = buf + (tid >> 6) * 384 + (tid & 63);   // stride-1 across lanes
    #pragma unroll
    for (int k = 0; k < WROWS; ++k) wp[k * 64] = cvtpk(pf.a[k], pf.b[k]);
}

// 512 threads = 8 waves; LDS 73.2 KB -> 2 blocks/CU, 16 waves/CU.
__global__ __launch_bounds__(512) __attribute__((amdgpu_waves_per_eu(4, 4)))
void fused_kernel(
    const float* __restrict__ x,
    const float* __restrict__ b_offset, const float* __restrict__ b_mask,
    const float* __restrict__ bn_gamma, const float* __restrict__ bn_beta,
    const float* __restrict__ bn_mean,  const float* __restrict__ bn_var,
    float* __restrict__ out)
{
    __shared__ unsigned short Atile[64][AP];     // 37120 B
    __shared__ unsigned win2[2][8 * 384];        // 2 x 12288 B: paired-bf16 window
    __shared__ float params[NPTS][5][64];        // 11520 B: gw0..3 + packed idx (R8-proven)
    float* ovf = (float*)&win2[0][0];            // px/py/m overlay between passes

    int blk = blockIdx.x;
    int b = blk >> 6, h = blk & 63;
    int tid  = threadIdx.x;
    int lane = tid & 63;
    int wv   = __builtin_amdgcn_readfirstlane(tid >> 6);  // wave 0..7
    int l15  = lane & 15;
    int kg   = lane >> 4;
    int spix = lane;

    const float* xb = x + (size_t)b * CC * HW;
    unsigned* AtU = (unsigned*)&Atile[0][0];     // row stride 145 uints (odd -> spread)

    // ================= PASS A: offset/mask conv (M=64,N=32,K=1152) =========
    int mi_a = wv & 3, nf_a = wv >> 2;
    f32x4 s1acc = {0.f, 0.f, 0.f, 0.f};

    int g = 0;
    PF pf; issue(pf, xb, h, 0, tid);
    for (int cb = 0; cb < 4; ++cb) {
        for (int s = 0; s < 2; ++s) {
            commit(win2[g & 1], pf, tid);
            __syncthreads();                 // window ready; prev-phase readers done
            issue(pf, xb, h, g + 1, tid);
            // build patch: word already holds the channel pair
            int cpair = s * 8 + wv;
            const unsigned* base = &win2[g & 1][wv * 384];
            #pragma unroll
            for (int tap = 0; tap < 9; ++tap) {
                int ky = tap / 3, kx = tap % 3;
                int col  = spix + kx - 1;
                int colc = min(max(col, 0), WW - 1);
                unsigned w = base[(ky + 1) * 64 + colc];
                w = (col >= 0 && col < WW) ? w : 0u;
                AtU[spix * 145 + cpair * 9 + tap] = w;
            }
            ++g;
        }
        __syncthreads();                     // Atile complete
        for (int q = 0; q < 9; ++q) {
            int koff = q * 32 + kg * 8;
            bf16x8 af = *(const bf16x8*)&Atile[mi_a * 16 + l15][koff];
            int nn = nf_a * 16 + l15;
            bf16x8 bfr = *(const bf16x8*)&g_woT[nn * KTOT + cb * BK + koff];
            s1acc = __builtin_amdgcn_mfma_f32_16x16x32_bf16(af, bfr, s1acc, 0, 0, 0);
        }
    }

    // ---- pass-A epilogue into overlay (win2[0] dead) -----------------------
    #pragma unroll
    for (int j = 0; j < 4; ++j) {
        float val = s1acc[j];
        int nn   = nf_a * 16 + l15;
        int pixl = mi_a * 16 + kg * 4 + j;
        if (nn < 9) {
            ovf[nn * 64 + pixl] = val + b_offset[nn] + (float)(nn / 3 - 1) + (float)(h + 1);
        } else if (nn < 18) {
            int n = nn - 9;
            ovf[576 + n * 64 + pixl] = val + b_offset[nn] + (float)(n % 3 - 1) + (float)(pixl + 1);
        } else if (nn < 27) {
            int n = nn - 18;
            float sg = val + b_mask[n];
            ovf[1152 + n * 64 + pixl] = 1.f / (1.f + expf(-sg));
        }
    }
    __syncthreads();

    // ================= param table: 64 threads -> LDS (R8 pattern) ==========
    // pk: bits0-12 o | bits13-19 (drow+64) | bits20-26 (dcol+64) | bit27 ok
    if (tid < 64) {
        int t = tid;
        #pragma unroll
        for (int n = 0; n < NPTS; ++n) {
            float px = ovf[n * 64 + t];
            float py = ovf[576 + n * 64 + t];
            float m  = ovf[1152 + n * 64 + t];
            float fx = floorf(px), fy = floorf(py);
            float qltx = fminf(fmaxf(fx,       0.f), 65.f);
            float qlty = fminf(fmaxf(fy,       0.f), 65.f);
            float qrbx = fminf(fmaxf(fx + 1.f, 0.f), 65.f);
            float qrby = fminf(fmaxf(fy + 1.f, 0.f), 65.f);
            float pxc  = fminf(fmaxf(px, 0.f), 65.f);
            float pyc  = fminf(fmaxf(py, 0.f), 65.f);
            float glt = (1.f + (qltx - pxc)) * (1.f + (qlty - pyc)) * m;
            float grb = (1.f - (qrbx - pxc)) * (1.f - (qrby - pyc)) * m;
            float glb = (1.f + (qltx - pxc)) * (1.f - (qrby - pyc)) * m;
            float grt = (1.f - (qrbx - pxc)) * (1.f + (qlty - pyc)) * m;
            int i0 = (int)qltx - 1, j0 = (int)qlty - 1;
            int i1 = (int)qrbx - 1, j1 = (int)qrby - 1;
            bool v00 = (i0 >= 0) & (i0 < HH) & (j0 >= 0) & (j0 < WW);
            bool v11 = (i1 >= 0) & (i1 < HH) & (j1 >= 0) & (j1 < WW);
            bool v01 = (i0 >= 0) & (i0 < HH) & (j1 >= 0) & (j1 < WW);
            bool v10 = (i1 >= 0) & (i1 < HH) & (j0 >= 0) & (j0 < WW);
            params[n][0][t] = v00 ? glt : 0.f;   // (i0,j0)
            params[n][1][t] = v11 ? grb : 0.f;   // (i1,j1)
            params[n][2][t] = v01 ? glb : 0.f;   // (i0,j1)
            params[n][3][t] = v10 ? grt : 0.f;   // (i1,j0)
            bool okr0 = ((i0 >= h - 2) & (i0 <= h + 3)) | !(v00 | v01);
            bool okr1 = ((i1 >= h - 2) & (i1 <= h + 3)) | !(v11 | v10);
            bool ok = okr0 & okr1;
            int r0w = min(max(i0 - (h - 2), 0), WROWS - 1);
            int r1w = min(max(i1 - (h - 2), 0), WROWS - 1);
            int r0g = min(max(i0, 0), HH - 1);
            int r1g = min(max(i1, 0), HH - 1);
            int j0c = min(max(j0, 0), WW - 1);
            int j1c = min(max(j1, 0), WW - 1);
            int o  = ok ? (r0w * WW + j0c) : (r0g * WW + j0c);
            int dr = ok ? (r1w - r0w) : (r1g - r0g);
            int dj = j1c - j0c;
            unsigned pk = (unsigned)o | ((unsigned)(dr + 64) << 13)
                        | ((unsigned)(dj + 64) << 20) | ((unsigned)ok << 27);
            params[n][4][t] = __builtin_bit_cast(float, pk);
        }
    }
    __syncthreads();                         // overlay dead; pass B may commit

    // ================= PASS B: main GEMM (M=64, N=256, K=1152) ==============
    f32x4 acc[4][2];
    #pragma unroll
    for (int mi = 0; mi < 4; ++mi)
        #pragma unroll
        for (int ni = 0; ni < 2; ++ni)
            acc[mi][ni] = (f32x4){0.f, 0.f, 0.f, 0.f};

    int oc0 = wv * 32;

    for (int cb = 0; cb < 4; ++cb) {
        for (int s = 0; s < 2; ++s) {
            commit(win2[g & 1], pf, tid);
            __syncthreads();
            issue(pf, xb, h, g + 1, tid);
            int cpair = s * 8 + wv;
            const unsigned* base = &win2[g & 1][wv * 384];
            const float* xgA = xb + (size_t)(cb * 32 + s * NCH + wv * 2) * HW;
            const float* xgB = xgA + HW;
            #pragma unroll
            for (int n = 0; n < NPTS; ++n) {
                float g0 = params[n][0][spix];
                float g1 = params[n][1][spix];
                float g2 = params[n][2][spix];
                float g3 = params[n][3][spix];
                unsigned p = __builtin_bit_cast(unsigned, params[n][4][spix]);
                int o  = p & 0x1FFF;
                int d1 = ((int)((p >> 13) & 0x7F) - 64) * WW;
                int d2 = (int)((p >> 20) & 0x7F) - 64;
                float v0, v1;
                if (p & (1u << 27)) {        // in-window: paired bf16 reads
                    unsigned w00 = base[o];
                    unsigned w11 = base[o + d1 + d2];
                    unsigned w01 = base[o + d2];
                    unsigned w10 = base[o + d1];
                    v0 =       g0 * bflo(w00);
                    v0 = fmaf(g1, bflo(w11), v0);
                    v0 = fmaf(g2, bflo(w01), v0);
                    v0 = fmaf(g3, bflo(w10), v0);
                    v1 =       g0 * bfhi(w00);
                    v1 = fmaf(g1, bfhi(w11), v1);
                    v1 = fmaf(g2, bfhi(w01), v1);
                    v1 = fmaf(g3, bfhi(w10), v1);
                } else {                     // rare: f32 global corners
                    v0 =       g0 * xgA[o];
                    v0 = fmaf(g1, xgA[o + d1 + d2], v0);
                    v0 = fmaf(g2, xgA[o + d2], v0);
                    v0 = fmaf(g3, xgA[o + d1], v0);
                    v1 =       g0 * xgB[o];
                    v1 = fmaf(g1, xgB[o + d1 + d2], v1);
                    v1 = fmaf(g2, xgB[o + d2], v1);
                    v1 = fmaf(g3, xgB[o + d1], v1);
                }
                AtU[spix * 145 + cpair * 9 + n] = cvtpk(v0, v1);
            }
            ++g;
        }
        __syncthreads();                     // Atile complete
        for (int q = 0; q < 9; ++q) {
            int koff = q * 32 + kg * 8;
            bf16x8 af[4];
            #pragma unroll
            for (int mi = 0; mi < 4; ++mi)
                af[mi] = *(const bf16x8*)&Atile[mi * 16 + l15][koff];
            #pragma unroll
            for (int ni = 0; ni < 2; ++ni) {
                int oc = oc0 + ni * 16 + l15;
                bf16x8 bfr = *(const bf16x8*)&g_wT[oc * KTOT + cb * BK + koff];
                #pragma unroll
                for (int mi = 0; mi < 4; ++mi)
                    acc[mi][ni] = __builtin_amdgcn_mfma_f32_16x16x32_bf16(af[mi], bfr, acc[mi][ni], 0, 0, 0);
            }
        }
    }

    // ================= epilogue: BN + ReLU, float4 stores ===================
    #pragma unroll
    for (int ni = 0; ni < 2; ++ni) {
        int oc = oc0 + ni * 16 + l15;
        float inv   = 1.f / sqrtf(bn_var[oc] + 1e-5f);
        float scale = bn_gamma[oc] * inv;
        float shift = bn_beta[oc] - bn_mean[oc] * scale;
        float* op = out + ((size_t)b * OUTC + oc) * HW + h * WW + kg * 4;
        #pragma unroll
        for (int mi = 0; mi < 4; ++mi) {
            f32x4 o4;
            #pragma unroll
            for (int j = 0; j < 4; ++j) {
                float v = fmaf(acc[mi][ni][j], scale, shift);
                o4[j] = v > 0.f ? v : 0.f;
            }
            *(f32x4*)(op + mi * 16) = o4;
        }
    }
}

extern "C" void kernel_launch(void* const* d_in, const int* in_sizes, int n_in,
                              void* d_out, int out_size, void* d_ws, size_t ws_size,
                              hipStream_t stream) {
    (void)in_sizes; (void)n_in; (void)out_size; (void)d_ws; (void)ws_size;
    const float* x        = (const float*)d_in[0];
    const float* w_offset = (const float*)d_in[1];
    const float* b_offset = (const float*)d_in[2];
    const float* w_mask   = (const float*)d_in[3];
    const float* b_mask   = (const float*)d_in[4];
    const float* w_conv   = (const float*)d_in[5];
    const float* bn_gamma = (const float*)d_in[6];
    const float* bn_beta  = (const float*)d_in[7];
    const float* bn_mean  = (const float*)d_in[8];
    const float* bn_var   = (const float*)d_in[9];
    float* out = (float*)d_out;

    int prep_elems = 32 * KTOT + OUTC * KTOT;
    prep_kernel<<<(prep_elems + 255) / 256, 256, 0, stream>>>(w_offset, w_mask, w_conv);
    fused_kernel<<<BB * HH, 512, 0, stream>>>(x, b_offset, b_mask,
                                              bn_gamma, bn_beta, bn_mean, bn_var, out);
}